// Round 10
// baseline (264.999 us; speedup 1.0000x reference)
//
#include <hip/hip_runtime.h>
#include <hip/hip_bf16.h>

// ---------------------------------------------------------------------------
// Attention_CA: out = Proj( Softmax(mask, scale * (q Wq^T) (kv Wkv^T)_K^T) (kv Wkv^T)_V )
// B=4, N=1024, M=2048, C=768, H=12, d=64.
// Round 10: prep kernel ELIMINATED — fp32->fp16 casts fused into gemm staging
// (weights never materialized in fp16; q/kv read fp32 once). Register staging
// (R6 pattern; gl_lds measured worse). attn = R6 structure (52.5us). 3 launches.
// ---------------------------------------------------------------------------

typedef short    s16x8  __attribute__((ext_vector_type(8)));
typedef short    s16x4  __attribute__((ext_vector_type(4)));
typedef float    f32x4  __attribute__((ext_vector_type(4)));
typedef _Float16 f16x8  __attribute__((ext_vector_type(8)));
typedef _Float16 f16x4  __attribute__((ext_vector_type(4)));
typedef _Float16 f16x2  __attribute__((ext_vector_type(2)));

#define NUM_H 12
#define DIM   768
#define NQ    1024
#define MK    2048
#define QK_SCALE_LOG2E 0.18033688f

__device__ __forceinline__ short f2h(float v) {
    _Float16 h = (_Float16)v;                 // RNE
    return __builtin_bit_cast(short, h);
}
__device__ __forceinline__ f32x4 mfma16x32(f16x8 a, f16x8 b, f32x4 c) {
    return __builtin_amdgcn_mfma_f32_16x16x32_f16(a, b, c, 0, 0, 0);
}
__device__ __forceinline__ f16x2 pk2h(float a, float b) {   // RTZ (P only)
    return __builtin_bit_cast(f16x2, __builtin_amdgcn_cvt_pkrtz(a, b));
}
__device__ __forceinline__ s16x8 cvt8(float4 a, float4 b) { // RNE fp32x8->fp16x8
    s16x8 r;
    r[0] = f2h(a.x); r[1] = f2h(a.y); r[2] = f2h(a.z); r[3] = f2h(a.w);
    r[4] = f2h(b.x); r[5] = f2h(b.y); r[6] = f2h(b.z); r[7] = f2h(b.w);
    return r;
}

// ---------------------------- GEMM core: C = A @ Bt^T ----------------------
// A: fp32 (modes 0/1, casts fused) or fp16 (mode 2). Bt: always fp32 weights.
// Register staging (R6), LDS stride 72, m fastest-varying block map.
// mode 0: qp scatter [B,H,N,d] fp16, *QK_SCALE_LOG2E
// mode 1: kv split -> K [B,H,M,d] fp16, V^T [B,H,d,M] fp16
// mode 2: out fp32 = v + bias[col]
template<bool A32>
__device__ __forceinline__ void gemm_core(
    short* smem, const void* Aptr, const float* Btf,
    int mtiles, int mode, const float* __restrict__ bias,
    short* __restrict__ outb, short* __restrict__ outb2,
    float* __restrict__ outf, int bid)
{
    short (*As)[72] = (short(*)[72])smem;
    short (*Bs)[72] = (short(*)[72])(smem + 9216);

    int m0 = (bid % mtiles) << 7;
    int n0 = (bid / mtiles) << 7;
    int t = threadIdx.x;
    int w = t >> 6, lane = t & 63, quad = lane >> 4, l16 = lane & 15;
    int wm = (w & 1) << 6, wn = (w >> 1) << 6;

    f32x4 zero4 = {0.f, 0.f, 0.f, 0.f};
    f32x4 acc[4][4];
    for (int i = 0; i < 4; i++)
        for (int j = 0; j < 4; j++) acc[i][j] = zero4;

    int lr = t >> 1;            // 0..127
    int lc = (t & 1) << 5;      // 0 or 32 (elements)
    const float* Af = (const float*)Aptr + (long)(m0 + lr) * DIM + lc;
    const short* Ah = (const short*)Aptr + (long)(m0 + lr) * DIM + lc;
    const float* Bf = Btf + (long)(n0 + lr) * DIM + lc;

    float4 a32[8]; s16x8 a16[4]; float4 b32[8];
    if (A32) {
        #pragma unroll
        for (int c = 0; c < 8; c++) a32[c] = *(const float4*)(Af + c * 4);
    } else {
        #pragma unroll
        for (int c = 0; c < 4; c++) a16[c] = *(const s16x8*)(Ah + c * 8);
    }
    #pragma unroll
    for (int c = 0; c < 8; c++) b32[c] = *(const float4*)(Bf + c * 4);

    for (int kt = 0; kt < DIM; kt += 64) {
        __syncthreads();
        #pragma unroll
        for (int c = 0; c < 4; c++) {
            s16x8 av = A32 ? cvt8(a32[2 * c], a32[2 * c + 1]) : a16[c];
            *(s16x8*)&As[lr][lc + c * 8] = av;
            *(s16x8*)&Bs[lr][lc + c * 8] = cvt8(b32[2 * c], b32[2 * c + 1]);
        }
        __syncthreads();
        if (kt + 64 < DIM) {
            if (A32) {
                #pragma unroll
                for (int c = 0; c < 8; c++)
                    a32[c] = *(const float4*)(Af + kt + 64 + c * 4);
            } else {
                #pragma unroll
                for (int c = 0; c < 4; c++)
                    a16[c] = *(const s16x8*)(Ah + kt + 64 + c * 8);
            }
            #pragma unroll
            for (int c = 0; c < 8; c++)
                b32[c] = *(const float4*)(Bf + kt + 64 + c * 4);
        }
        #pragma unroll
        for (int kh = 0; kh < 2; kh++) {
            f16x8 af[4], bfr[4];
            #pragma unroll
            for (int i = 0; i < 4; i++)
                af[i] = __builtin_bit_cast(f16x8,
                    *(const s16x8*)&As[wm + i * 16 + l16][kh * 32 + quad * 8]);
            #pragma unroll
            for (int j = 0; j < 4; j++)
                bfr[j] = __builtin_bit_cast(f16x8,
                    *(const s16x8*)&Bs[wn + j * 16 + l16][kh * 32 + quad * 8]);
            #pragma unroll
            for (int i = 0; i < 4; i++)
                #pragma unroll
                for (int j = 0; j < 4; j++)
                    acc[i][j] = mfma16x32(af[i], bfr[j], acc[i][j]);
        }
    }

    __syncthreads();   // MFMA LDS reads done; smem reusable

    if (mode == 2) {
        #pragma unroll
        for (int i = 0; i < 4; i++)
            #pragma unroll
            for (int j = 0; j < 4; j++)
                #pragma unroll
                for (int r = 0; r < 4; r++) {
                    int row = m0 + wm + i * 16 + quad * 4 + r;
                    int col = n0 + wn + j * 16 + l16;
                    outf[(long)row * DIM + col] = acc[i][j][r] + bias[col];
                }
        return;
    }

    short (*Cs)[136] = (short(*)[136])smem;
    bool vreg = (mode == 1) && (n0 >= DIM);

    if (!vreg) {
        float sc = (mode == 0) ? QK_SCALE_LOG2E : 1.0f;
        #pragma unroll
        for (int i = 0; i < 4; i++)
            #pragma unroll
            for (int j = 0; j < 4; j++)
                #pragma unroll
                for (int r = 0; r < 4; r++)
                    Cs[wm + i * 16 + quad * 4 + r][wn + j * 16 + l16] =
                        f2h(acc[i][j][r] * sc);
    } else {
        #pragma unroll
        for (int i = 0; i < 4; i++)
            #pragma unroll
            for (int j = 0; j < 4; j++) {
                int c = wn + j * 16 + l16;
                int r0 = wm + i * 16 + quad * 4;
                s16x4 pk;
                pk[0] = f2h(acc[i][j][0]); pk[1] = f2h(acc[i][j][1]);
                pk[2] = f2h(acc[i][j][2]); pk[3] = f2h(acc[i][j][3]);
                *(s16x4*)&Cs[c][r0] = pk;            // transposed: Cs[dd][m]
            }
    }
    __syncthreads();

    if (!vreg) {
        int hb2 = n0 >> 6;
        long rowsN = (mode == 0) ? NQ : MK;
        int b = (int)(m0 / rowsN);
        int rb = (int)(m0 % rowsN);
        short* ob0 = outb + ((long)(b * NUM_H + hb2) * rowsN + rb) * 64;
        short* ob1 = outb + ((long)(b * NUM_H + hb2 + 1) * rowsN + rb) * 64;
        #pragma unroll
        for (int k2 = 0; k2 < 8; k2++) {
            int ch = k2 * 256 + t;
            int half = ch >> 10, off = ch & 1023;
            s16x8 vd = *(const s16x8*)&Cs[off >> 3][(half << 6) + ((off & 7) << 3)];
            *(s16x8*)((half ? ob1 : ob0) + off * 8) = vd;
        }
    } else {
        int hb2 = (n0 - DIM) >> 6;
        int b = m0 >> 11, rb = m0 & 2047;
        #pragma unroll
        for (int k2 = 0; k2 < 8; k2++) {
            int ch = k2 * 256 + t;
            int c = ch >> 4, woff = (ch & 15) << 3;
            s16x8 vd = *(const s16x8*)&Cs[c][woff];
            int half = c >> 6, dd = c & 63;
            *(s16x8*)(outb2 + (((long)(b * NUM_H + hb2 + half) * 64 + dd) * MK + rb) + woff) = vd;
        }
    }
}

// gemm12 (q-proj + kv-proj, fp32 inputs) + fused mask byte-pack tail blocks
__global__ __launch_bounds__(256) void gemm12_kernel(
    const float* __restrict__ q, const float* __restrict__ Wq,
    const float* __restrict__ kv, const float* __restrict__ Wkv,
    short* __restrict__ qp, short* __restrict__ kk, short* __restrict__ vt,
    const int* __restrict__ mask, unsigned char* __restrict__ mbytes)
{
    __shared__ short smem[18432];
    int bid = blockIdx.x;
    if (bid >= 960) {
        long base = (long)(bid - 960) * 2048 + threadIdx.x * 8;
        int4 m0 = *(const int4*)(mask + base);
        int4 m1 = *(const int4*)(mask + base + 4);
        unsigned v = (unsigned)(m0.x != 0)        | ((unsigned)(m0.y != 0) << 1)
                   | ((unsigned)(m0.z != 0) << 2) | ((unsigned)(m0.w != 0) << 3)
                   | ((unsigned)(m1.x != 0) << 4) | ((unsigned)(m1.y != 0) << 5)
                   | ((unsigned)(m1.z != 0) << 6) | ((unsigned)(m1.w != 0) << 7);
        mbytes[base >> 3] = (unsigned char)v;
        return;
    }
    if (bid < 192)
        gemm_core<true>(smem, q, Wq, 32, 0, nullptr, qp, nullptr, nullptr, bid);
    else
        gemm_core<true>(smem, kv, Wkv, 64, 1, nullptr, kk, vt, nullptr, bid - 192);
}

__global__ __launch_bounds__(256) void gemm3_kernel(
    const short* __restrict__ xb, const float* __restrict__ Wp,
    const float* __restrict__ bias, float* __restrict__ out)
{
    __shared__ short smem[18432];
    gemm_core<false>(smem, xb, Wp, 32, 2, bias, nullptr, nullptr, out, blockIdx.x);
}

// ------------------------- flash attention (R6, 52.5us) --------------------
// 4 waves x 16 q-rows. K-tile rows PERMUTED at staging so S^T lands in fp16
// K=32 A-fragment order -> PV: 10x mfma_16x16x32, V frags via ds_read_b128.
__global__ __launch_bounds__(256) void attn_kernel(
    const short* __restrict__ qp, const short* __restrict__ kk,
    const short* __restrict__ vt, const unsigned* __restrict__ mb,
    short* __restrict__ xb)
{
    __shared__ short qs[64][72];       // Q tile; reused as O staging
    __shared__ short ks[64][72];       // K tile, rows permuted
    __shared__ short vs[64][72];       // V^T tile [dd][m]

    int bid = blockIdx.x;
    int bh = bid % 48;                 // XCD swizzle: head bh -> XCD bh%8
    int nt = bid / 48;
    int h = bh % NUM_H, b = bh / NUM_H;
    int n0 = nt << 6;
    int t = threadIdx.x, w = t >> 6, lane = t & 63, quad = lane >> 4, l16 = lane & 15;

    const short* qbase = qp + ((long)bh * NQ + n0) * 64;
    const short* kbase = kk + (long)bh * MK * 64;
    const short* vbase = vt + (long)bh * 64 * MK;
    const unsigned* mrow = mb + ((long)b * NQ + n0 + (w << 4) + l16) * 64;

    {   // stage Q tile once
        int qr = t >> 2, c0 = (t & 3) << 4;
        *(s16x8*)&qs[qr][c0]     = *(const s16x8*)(qbase + qr * 64 + c0);
        *(s16x8*)&qs[qr][c0 + 8] = *(const s16x8*)(qbase + qr * 64 + c0 + 8);
    }
    __syncthreads();
    f16x8 bq[2];                       // B-frag: this wave's 16 q-rows
    #pragma unroll
    for (int kh = 0; kh < 2; kh++)
        bq[kh] = __builtin_bit_cast(f16x8,
            *(const s16x8*)&qs[(w << 4) + l16][kh * 32 + quad * 8]);

    int sr = t >> 2, c0 = (t & 3) << 4;
    int pr = (sr & 32) + ((sr & 4) << 2) + ((sr & 24) >> 1) + (sr & 3);
    const short* kp = kbase + (long)sr * 64 + c0;
    const short* vp = vbase + (long)sr * MK + c0;

    s16x8 k0 = *(const s16x8*)(kp);
    s16x8 k1 = *(const s16x8*)(kp + 8);
    s16x8 v0 = *(const s16x8*)(vp);
    s16x8 v1 = *(const s16x8*)(vp + 8);
    uint2 mwv = *(const uint2*)(mrow);

    f32x4 zero4 = {0.f, 0.f, 0.f, 0.f};
    f32x4 o[4], ol = zero4;
    for (int j = 0; j < 4; j++) o[j] = zero4;
    const f16x8 ones = {(_Float16)1.f, (_Float16)1.f, (_Float16)1.f, (_Float16)1.f,
                        (_Float16)1.f, (_Float16)1.f, (_Float16)1.f, (_Float16)1.f};

    for (int mt = 0; mt < MK; mt += 64) {
        __syncthreads();
        *(s16x8*)&ks[pr][c0]     = k0;
        *(s16x8*)&ks[pr][c0 + 8] = k1;
        *(s16x8*)&vs[sr][c0]     = v0;
        *(s16x8*)&vs[sr][c0 + 8] = v1;
        unsigned cm0 = mwv.x, cm1 = mwv.y;      // save pre-clobber
        __syncthreads();
        if (mt + 64 < MK) {
            k0 = *(const s16x8*)(kp + (long)(mt + 64) * 64);
            k1 = *(const s16x8*)(kp + (long)(mt + 64) * 64 + 8);
            v0 = *(const s16x8*)(vp + mt + 64);
            v1 = *(const s16x8*)(vp + mt + 64 + 8);
            mwv = *(const uint2*)(mrow + ((mt + 64) >> 5));
        }

        // S^T = K Q^T; s[jj=j2*2+sub][rr] = S[qrow=l16][m=j2*32+quad*8+sub*4+rr]
        f32x4 s[4];
        #pragma unroll
        for (int jj = 0; jj < 4; jj++) s[jj] = zero4;
        #pragma unroll
        for (int kh = 0; kh < 2; kh++)
            #pragma unroll
            for (int jj = 0; jj < 4; jj++) {
                f16x8 ak = __builtin_bit_cast(f16x8,
                    *(const s16x8*)&ks[jj * 16 + l16][kh * 32 + quad * 8]);
                s[jj] = mfma16x32(ak, bq[kh], s[jj]);
            }

        // p = mask ? exp2(s) : 0, packed to K=32 fp16 A-fragments
        f16x8 pa[2];
        #pragma unroll
        for (int j2 = 0; j2 < 2; j2++) {
            unsigned wsel = j2 ? cm1 : cm0;
            f16x2 pk[4];
            #pragma unroll
            for (int sub = 0; sub < 2; sub++) {
                unsigned bits = wsel >> ((quad << 3) + (sub << 2));
                const f32x4& sv = s[j2 * 2 + sub];
                float p0 = (bits & 1u)        ? __builtin_amdgcn_exp2f(sv[0]) : 0.f;
                float p1 = ((bits >> 1) & 1u) ? __builtin_amdgcn_exp2f(sv[1]) : 0.f;
                float p2 = ((bits >> 2) & 1u) ? __builtin_amdgcn_exp2f(sv[2]) : 0.f;
                float p3 = ((bits >> 3) & 1u) ? __builtin_amdgcn_exp2f(sv[3]) : 0.f;
                pk[sub * 2]     = pk2h(p0, p1);
                pk[sub * 2 + 1] = pk2h(p2, p3);
            }
            f16x4 lo = __builtin_shufflevector(pk[0], pk[1], 0, 1, 2, 3);
            f16x4 hi = __builtin_shufflevector(pk[2], pk[3], 0, 1, 2, 3);
            pa[j2] = __builtin_shufflevector(lo, hi, 0, 1, 2, 3, 4, 5, 6, 7);
        }

        // O += P V ; l += P ones   (K=32: 10 MFMAs, V frags via b128)
        #pragma unroll
        for (int j2 = 0; j2 < 2; j2++) {
            ol = mfma16x32(pa[j2], ones, ol);
            #pragma unroll
            for (int jd = 0; jd < 4; jd++) {
                f16x8 bv = __builtin_bit_cast(f16x8,
                    *(const s16x8*)&vs[jd * 16 + l16][j2 * 32 + quad * 8]);
                o[jd] = mfma16x32(pa[j2], bv, o[jd]);
            }
        }
    }

    // epilogue: normalize, stage via this wave's 16 qs rows, coalesced store
    float linv[4];
    #pragma unroll
    for (int rr = 0; rr < 4; rr++) linv[rr] = 1.0f / ol[rr];
    short (*ps)[72] = (short(*)[72])&qs[w << 4];   // wave-private 16 rows
    #pragma unroll
    for (int jd = 0; jd < 4; jd++)
        #pragma unroll
        for (int rr = 0; rr < 4; rr++)
            ps[quad * 4 + rr][jd * 16 + l16] = f2h(o[jd][rr] * linv[rr]);

    #pragma unroll
    for (int k2 = 0; k2 < 2; k2++) {
        int row = (lane >> 3) + k2 * 8;
        int cc = (lane & 7) << 3;
        s16x8 vd = *(const s16x8*)&ps[row][cc];
        *(s16x8*)(xb + ((long)b * NQ + n0 + (w << 4) + row) * DIM + h * 64 + cc) = vd;
    }
}

// ---------------------------------------------------------------------------
extern "C" void kernel_launch(void* const* d_in, const int* in_sizes, int n_in,
                              void* d_out, int out_size, void* d_ws, size_t ws_size,
                              hipStream_t stream)
{
    const float* q     = (const float*)d_in[0];
    const float* kv    = (const float*)d_in[1];
    const float* Wq    = (const float*)d_in[2];
    const float* Wkv   = (const float*)d_in[3];
    const float* Wproj = (const float*)d_in[4];
    const float* bproj = (const float*)d_in[5];
    const int*   mask  = (const int*)d_in[6];
    float* out = (float*)d_out;

    char* ws = (char*)d_ws;
    short* qp = (short*)ws; ws += (size_t)4096 * 768 * 2;   // [B,H,N,64] fp16
    short* kk = (short*)ws; ws += (size_t)8192 * 768 * 2;   // [B,H,M,64] fp16
    short* vt = (short*)ws; ws += (size_t)8192 * 768 * 2;   // [B,H,64,M] fp16
    short* xb = (short*)ws; ws += (size_t)4096 * 768 * 2;   // [B,N,768]  fp16
    unsigned char* mbytes = (unsigned char*)ws;             // [B,N,M/8] = 1 MB

    gemm12_kernel<<<5056, 256, 0, stream>>>(q, Wq, kv, Wkv,
                                            qp, kk, vt, mask, mbytes);
    attn_kernel<<<768, 256, 0, stream>>>(qp, kk, vt, (const unsigned*)mbytes, xb);
    gemm3_kernel<<<192, 256, 0, stream>>>(xb, Wproj, bproj, out);
}

// Round 11
// 214.364 us; speedup vs baseline: 1.2362x; 1.2362x over previous
//
#include <hip/hip_runtime.h>
#include <hip/hip_bf16.h>

// ---------------------------------------------------------------------------
// Attention_CA: out = Proj( Softmax(mask, scale * (q Wq^T) (kv Wkv^T)_K^T) (kv Wkv^T)_V )
// B=4, N=1024, M=2048, C=768, H=12, d=64.
// Round 11: R6 structure restored (best: 216.4us; R10 fused-cast gemm was
// latency-bound at MfmaUtil 8.6%). gemm_core now 2-deep ping-pong register
// pipeline: each global load gets ~2 barrier intervals in flight before its
// LDS store consumes it (covers L3 latency). attn = R6 (52.5us). fp16, fp32 acc.
// ---------------------------------------------------------------------------

typedef short    s16x8  __attribute__((ext_vector_type(8)));
typedef short    s16x4  __attribute__((ext_vector_type(4)));
typedef float    f32x4  __attribute__((ext_vector_type(4)));
typedef _Float16 f16x8  __attribute__((ext_vector_type(8)));
typedef _Float16 f16x4  __attribute__((ext_vector_type(4)));
typedef _Float16 f16x2  __attribute__((ext_vector_type(2)));

#define NUM_H 12
#define DIM   768
#define NQ    1024
#define MK    2048
#define QK_SCALE_LOG2E 0.18033688f

__device__ __forceinline__ short f2h(float v) {
    _Float16 h = (_Float16)v;                 // RNE
    return __builtin_bit_cast(short, h);
}
__device__ __forceinline__ f32x4 mfma16x32(f16x8 a, f16x8 b, f32x4 c) {
    return __builtin_amdgcn_mfma_f32_16x16x32_f16(a, b, c, 0, 0, 0);
}
__device__ __forceinline__ f16x2 pk2h(float a, float b) {   // RTZ (P only)
    return __builtin_bit_cast(f16x2, __builtin_amdgcn_cvt_pkrtz(a, b));
}

// ------------------- prep: all casts + mask byte-pack ----------------------
__global__ __launch_bounds__(256) void prep_kernel(
    const float* __restrict__ q, const float* __restrict__ kv,
    const float* __restrict__ Wq, const float* __restrict__ Wkv,
    const float* __restrict__ Wp, const int* __restrict__ mask,
    short* __restrict__ q_h, short* __restrict__ kv_h,
    short* __restrict__ Wq_h, short* __restrict__ Wkv_h,
    short* __restrict__ Wp_h, unsigned char* __restrict__ mbytes)
{
    int bid = blockIdx.x;
    if (bid < 5760) {
        const float* s; short* d; long base;
        if (bid < 1536)      { s = q;   d = q_h;   base = (long)bid * 2048; }
        else if (bid < 4608) { s = kv;  d = kv_h;  base = (long)(bid - 1536) * 2048; }
        else if (bid < 4896) { s = Wq;  d = Wq_h;  base = (long)(bid - 4608) * 2048; }
        else if (bid < 5472) { s = Wkv; d = Wkv_h; base = (long)(bid - 4896) * 2048; }
        else                 { s = Wp;  d = Wp_h;  base = (long)(bid - 5472) * 2048; }
        long i = base + threadIdx.x * 8;
        float4 a = *(const float4*)(s + i);
        float4 b = *(const float4*)(s + i + 4);
        s16x8 r;
        r[0] = f2h(a.x); r[1] = f2h(a.y); r[2] = f2h(a.z); r[3] = f2h(a.w);
        r[4] = f2h(b.x); r[5] = f2h(b.y); r[6] = f2h(b.z); r[7] = f2h(b.w);
        *(s16x8*)(d + i) = r;
    } else {
        long base = (long)(bid - 5760) * 2048 + threadIdx.x * 8;
        int4 m0 = *(const int4*)(mask + base);
        int4 m1 = *(const int4*)(mask + base + 4);
        unsigned v = (unsigned)(m0.x != 0)        | ((unsigned)(m0.y != 0) << 1)
                   | ((unsigned)(m0.z != 0) << 2) | ((unsigned)(m0.w != 0) << 3)
                   | ((unsigned)(m1.x != 0) << 4) | ((unsigned)(m1.y != 0) << 5)
                   | ((unsigned)(m1.z != 0) << 6) | ((unsigned)(m1.w != 0) << 7);
        mbytes[base >> 3] = (unsigned char)v;
    }
}

// ---------------------------- GEMM core: C = A @ Bt^T ----------------------
// 2-deep ping-pong register pipeline (covers L3 latency; gemm was
// latency-bound at MfmaUtil<10% with 1-deep prefetch).
// mode 0: qp scatter [B,H,N,d] fp16, *QK_SCALE_LOG2E
// mode 1: kv split -> K [B,H,M,d] fp16, V^T [B,H,d,M] fp16
// mode 2: out fp32 = v + bias[col]
__device__ __forceinline__ void gemm_core(
    short* smem,
    const short* __restrict__ A, const short* __restrict__ Bt,
    int Ncols, int mode, const float* __restrict__ bias,
    short* __restrict__ outb, short* __restrict__ outb2,
    float* __restrict__ outf, int bid)
{
    short (*As)[72] = (short(*)[72])smem;
    short (*Bs)[72] = (short(*)[72])(smem + 9216);

    int ntiles = Ncols >> 7;
    int m0 = (bid / ntiles) << 7;
    int n0 = (bid % ntiles) << 7;
    int t = threadIdx.x;
    int w = t >> 6, lane = t & 63, quad = lane >> 4, l16 = lane & 15;
    int wm = (w & 1) << 6, wn = (w >> 1) << 6;

    f32x4 zero4 = {0.f, 0.f, 0.f, 0.f};
    f32x4 acc[4][4];
    for (int i = 0; i < 4; i++)
        for (int j = 0; j < 4; j++) acc[i][j] = zero4;

    int lr = t >> 1;            // 0..127
    int lc = (t & 1) << 5;      // 0 or 32
    const short* Ap = A + (long)(m0 + lr) * DIM + lc;
    const short* Bp = Bt + (long)(n0 + lr) * DIM + lc;

    // two K-sub-tiles in flight (ping-pong, no register copies)
    s16x8 a0[4], b0[4], a1[4], b1[4];
    #pragma unroll
    for (int c = 0; c < 4; c++) {
        a0[c] = *(const s16x8*)(Ap + c * 8);
        b0[c] = *(const s16x8*)(Bp + c * 8);
        a1[c] = *(const s16x8*)(Ap + 64 + c * 8);
        b1[c] = *(const s16x8*)(Bp + 64 + c * 8);
    }

    auto mfma_tile = [&]() {
        #pragma unroll
        for (int kh = 0; kh < 2; kh++) {
            f16x8 af[4], bfr[4];
            #pragma unroll
            for (int i = 0; i < 4; i++)
                af[i] = __builtin_bit_cast(f16x8,
                    *(const s16x8*)&As[wm + i * 16 + l16][kh * 32 + quad * 8]);
            #pragma unroll
            for (int j = 0; j < 4; j++)
                bfr[j] = __builtin_bit_cast(f16x8,
                    *(const s16x8*)&Bs[wn + j * 16 + l16][kh * 32 + quad * 8]);
            #pragma unroll
            for (int i = 0; i < 4; i++)
                #pragma unroll
                for (int j = 0; j < 4; j++)
                    acc[i][j] = mfma16x32(af[i], bfr[j], acc[i][j]);
        }
    };

    for (int kt = 0; kt < DIM; kt += 128) {
        // ---- sub-tile kt (buffer 0) ----
        __syncthreads();
        #pragma unroll
        for (int c = 0; c < 4; c++) {
            *(s16x8*)&As[lr][lc + c * 8] = a0[c];
            *(s16x8*)&Bs[lr][lc + c * 8] = b0[c];
        }
        __syncthreads();
        if (kt + 128 < DIM) {
            #pragma unroll
            for (int c = 0; c < 4; c++) {
                a0[c] = *(const s16x8*)(Ap + kt + 128 + c * 8);
                b0[c] = *(const s16x8*)(Bp + kt + 128 + c * 8);
            }
        }
        mfma_tile();
        // ---- sub-tile kt+64 (buffer 1) ----
        __syncthreads();
        #pragma unroll
        for (int c = 0; c < 4; c++) {
            *(s16x8*)&As[lr][lc + c * 8] = a1[c];
            *(s16x8*)&Bs[lr][lc + c * 8] = b1[c];
        }
        __syncthreads();
        if (kt + 192 < DIM) {
            #pragma unroll
            for (int c = 0; c < 4; c++) {
                a1[c] = *(const s16x8*)(Ap + kt + 192 + c * 8);
                b1[c] = *(const s16x8*)(Bp + kt + 192 + c * 8);
            }
        }
        mfma_tile();
    }

    __syncthreads();   // MFMA LDS reads done; smem reusable

    if (mode == 2) {
        #pragma unroll
        for (int i = 0; i < 4; i++)
            #pragma unroll
            for (int j = 0; j < 4; j++)
                #pragma unroll
                for (int r = 0; r < 4; r++) {
                    int row = m0 + wm + i * 16 + quad * 4 + r;
                    int col = n0 + wn + j * 16 + l16;
                    outf[(long)row * DIM + col] = acc[i][j][r] + bias[col];
                }
        return;
    }

    short (*Cs)[136] = (short(*)[136])smem;
    bool vreg = (mode == 1) && (n0 >= DIM);

    if (!vreg) {
        float sc = (mode == 0) ? QK_SCALE_LOG2E : 1.0f;
        #pragma unroll
        for (int i = 0; i < 4; i++)
            #pragma unroll
            for (int j = 0; j < 4; j++)
                #pragma unroll
                for (int r = 0; r < 4; r++)
                    Cs[wm + i * 16 + quad * 4 + r][wn + j * 16 + l16] =
                        f2h(acc[i][j][r] * sc);
    } else {
        #pragma unroll
        for (int i = 0; i < 4; i++)
            #pragma unroll
            for (int j = 0; j < 4; j++) {
                int c = wn + j * 16 + l16;
                int r0 = wm + i * 16 + quad * 4;
                s16x4 pk;
                pk[0] = f2h(acc[i][j][0]); pk[1] = f2h(acc[i][j][1]);
                pk[2] = f2h(acc[i][j][2]); pk[3] = f2h(acc[i][j][3]);
                *(s16x4*)&Cs[c][r0] = pk;            // transposed: Cs[dd][m]
            }
    }
    __syncthreads();

    if (!vreg) {
        int hb2 = n0 >> 6;
        long rowsN = (mode == 0) ? NQ : MK;
        int b = (int)(m0 / rowsN);
        int rb = (int)(m0 % rowsN);
        short* ob0 = outb + ((long)(b * NUM_H + hb2) * rowsN + rb) * 64;
        short* ob1 = outb + ((long)(b * NUM_H + hb2 + 1) * rowsN + rb) * 64;
        #pragma unroll
        for (int k2 = 0; k2 < 8; k2++) {
            int ch = k2 * 256 + t;
            int half = ch >> 10, off = ch & 1023;
            s16x8 vd = *(const s16x8*)&Cs[off >> 3][(half << 6) + ((off & 7) << 3)];
            *(s16x8*)((half ? ob1 : ob0) + off * 8) = vd;
        }
    } else {
        int hb2 = (n0 - DIM) >> 6;
        int b = m0 >> 11, rb = m0 & 2047;
        #pragma unroll
        for (int k2 = 0; k2 < 8; k2++) {
            int ch = k2 * 256 + t;
            int c = ch >> 4, woff = (ch & 15) << 3;
            s16x8 vd = *(const s16x8*)&Cs[c][woff];
            int half = c >> 6, dd = c & 63;
            *(s16x8*)(outb2 + (((long)(b * NUM_H + hb2 + half) * 64 + dd) * MK + rb) + woff) = vd;
        }
    }
}

__global__ __launch_bounds__(256) void gemm12_kernel(
    const short* __restrict__ qh, const short* __restrict__ Wqh,
    const short* __restrict__ kvh, const short* __restrict__ Wkvh,
    short* __restrict__ qp, short* __restrict__ kk, short* __restrict__ vt)
{
    __shared__ short smem[18432];
    if (blockIdx.x < 192)
        gemm_core(smem, qh, Wqh, 768, 0, nullptr, qp, nullptr, nullptr, blockIdx.x);
    else
        gemm_core(smem, kvh, Wkvh, 1536, 1, nullptr, kk, vt, nullptr, blockIdx.x - 192);
}

__global__ __launch_bounds__(256) void gemm3_kernel(
    const short* __restrict__ xb, const short* __restrict__ Wph,
    const float* __restrict__ bias, float* __restrict__ out)
{
    __shared__ short smem[18432];
    gemm_core(smem, xb, Wph, 768, 2, bias, nullptr, nullptr, out, blockIdx.x);
}

// ------------------------- flash attention (R6, 52.5us) --------------------
// 4 waves x 16 q-rows. K-tile rows PERMUTED at staging so S^T lands in fp16
// K=32 A-fragment order -> PV: 10x mfma_16x16x32, V frags via ds_read_b128.
__global__ __launch_bounds__(256) void attn_kernel(
    const short* __restrict__ qp, const short* __restrict__ kk,
    const short* __restrict__ vt, const unsigned* __restrict__ mb,
    short* __restrict__ xb)
{
    __shared__ short qs[64][72];       // Q tile; reused as O staging
    __shared__ short ks[64][72];       // K tile, rows permuted
    __shared__ short vs[64][72];       // V^T tile [dd][m]

    int bid = blockIdx.x;
    int bh = bid % 48;                 // XCD swizzle: head bh -> XCD bh%8
    int nt = bid / 48;
    int h = bh % NUM_H, b = bh / NUM_H;
    int n0 = nt << 6;
    int t = threadIdx.x, w = t >> 6, lane = t & 63, quad = lane >> 4, l16 = lane & 15;

    const short* qbase = qp + ((long)bh * NQ + n0) * 64;
    const short* kbase = kk + (long)bh * MK * 64;
    const short* vbase = vt + (long)bh * 64 * MK;
    const unsigned* mrow = mb + ((long)b * NQ + n0 + (w << 4) + l16) * 64;

    {   // stage Q tile once
        int qr = t >> 2, c0 = (t & 3) << 4;
        *(s16x8*)&qs[qr][c0]     = *(const s16x8*)(qbase + qr * 64 + c0);
        *(s16x8*)&qs[qr][c0 + 8] = *(const s16x8*)(qbase + qr * 64 + c0 + 8);
    }
    __syncthreads();
    f16x8 bq[2];                       // B-frag: this wave's 16 q-rows
    #pragma unroll
    for (int kh = 0; kh < 2; kh++)
        bq[kh] = __builtin_bit_cast(f16x8,
            *(const s16x8*)&qs[(w << 4) + l16][kh * 32 + quad * 8]);

    int sr = t >> 2, c0 = (t & 3) << 4;
    int pr = (sr & 32) + ((sr & 4) << 2) + ((sr & 24) >> 1) + (sr & 3);
    const short* kp = kbase + (long)sr * 64 + c0;
    const short* vp = vbase + (long)sr * MK + c0;

    s16x8 k0 = *(const s16x8*)(kp);
    s16x8 k1 = *(const s16x8*)(kp + 8);
    s16x8 v0 = *(const s16x8*)(vp);
    s16x8 v1 = *(const s16x8*)(vp + 8);
    uint2 mwv = *(const uint2*)(mrow);

    f32x4 zero4 = {0.f, 0.f, 0.f, 0.f};
    f32x4 o[4], ol = zero4;
    for (int j = 0; j < 4; j++) o[j] = zero4;
    const f16x8 ones = {(_Float16)1.f, (_Float16)1.f, (_Float16)1.f, (_Float16)1.f,
                        (_Float16)1.f, (_Float16)1.f, (_Float16)1.f, (_Float16)1.f};

    for (int mt = 0; mt < MK; mt += 64) {
        __syncthreads();
        *(s16x8*)&ks[pr][c0]     = k0;
        *(s16x8*)&ks[pr][c0 + 8] = k1;
        *(s16x8*)&vs[sr][c0]     = v0;
        *(s16x8*)&vs[sr][c0 + 8] = v1;
        unsigned cm0 = mwv.x, cm1 = mwv.y;      // save pre-clobber
        __syncthreads();
        if (mt + 64 < MK) {
            k0 = *(const s16x8*)(kp + (long)(mt + 64) * 64);
            k1 = *(const s16x8*)(kp + (long)(mt + 64) * 64 + 8);
            v0 = *(const s16x8*)(vp + mt + 64);
            v1 = *(const s16x8*)(vp + mt + 64 + 8);
            mwv = *(const uint2*)(mrow + ((mt + 64) >> 5));
        }

        // S^T = K Q^T; s[jj=j2*2+sub][rr] = S[qrow=l16][m=j2*32+quad*8+sub*4+rr]
        f32x4 s[4];
        #pragma unroll
        for (int jj = 0; jj < 4; jj++) s[jj] = zero4;
        #pragma unroll
        for (int kh = 0; kh < 2; kh++)
            #pragma unroll
            for (int jj = 0; jj < 4; jj++) {
                f16x8 ak = __builtin_bit_cast(f16x8,
                    *(const s16x8*)&ks[jj * 16 + l16][kh * 32 + quad * 8]);
                s[jj] = mfma16x32(ak, bq[kh], s[jj]);
            }

        // p = mask ? exp2(s) : 0, packed to K=32 fp16 A-fragments
        f16x8 pa[2];
        #pragma unroll
        for (int j2 = 0; j2 < 2; j2++) {
            unsigned wsel = j2 ? cm1 : cm0;
            f16x2 pk[4];
            #pragma unroll
            for (int sub = 0; sub < 2; sub++) {
                unsigned bits = wsel >> ((quad << 3) + (sub << 2));
                const f32x4& sv = s[j2 * 2 + sub];
                float p0 = (bits & 1u)        ? __builtin_amdgcn_exp2f(sv[0]) : 0.f;
                float p1 = ((bits >> 1) & 1u) ? __builtin_amdgcn_exp2f(sv[1]) : 0.f;
                float p2 = ((bits >> 2) & 1u) ? __builtin_amdgcn_exp2f(sv[2]) : 0.f;
                float p3 = ((bits >> 3) & 1u) ? __builtin_amdgcn_exp2f(sv[3]) : 0.f;
                pk[sub * 2]     = pk2h(p0, p1);
                pk[sub * 2 + 1] = pk2h(p2, p3);
            }
            f16x4 lo = __builtin_shufflevector(pk[0], pk[1], 0, 1, 2, 3);
            f16x4 hi = __builtin_shufflevector(pk[2], pk[3], 0, 1, 2, 3);
            pa[j2] = __builtin_shufflevector(lo, hi, 0, 1, 2, 3, 4, 5, 6, 7);
        }

        // O += P V ; l += P ones   (K=32: 10 MFMAs, V frags via b128)
        #pragma unroll
        for (int j2 = 0; j2 < 2; j2++) {
            ol = mfma16x32(pa[j2], ones, ol);
            #pragma unroll
            for (int jd = 0; jd < 4; jd++) {
                f16x8 bv = __builtin_bit_cast(f16x8,
                    *(const s16x8*)&vs[jd * 16 + l16][j2 * 32 + quad * 8]);
                o[jd] = mfma16x32(pa[j2], bv, o[jd]);
            }
        }
    }

    // epilogue: normalize, stage via this wave's 16 qs rows, coalesced store
    float linv[4];
    #pragma unroll
    for (int rr = 0; rr < 4; rr++) linv[rr] = 1.0f / ol[rr];
    short (*ps)[72] = (short(*)[72])&qs[w << 4];   // wave-private 16 rows
    #pragma unroll
    for (int jd = 0; jd < 4; jd++)
        #pragma unroll
        for (int rr = 0; rr < 4; rr++)
            ps[quad * 4 + rr][jd * 16 + l16] = f2h(o[jd][rr] * linv[rr]);

    #pragma unroll
    for (int k2 = 0; k2 < 2; k2++) {
        int row = (lane >> 3) + k2 * 8;
        int cc = (lane & 7) << 3;
        s16x8 vd = *(const s16x8*)&ps[row][cc];
        *(s16x8*)(xb + ((long)b * NQ + n0 + (w << 4) + row) * DIM + h * 64 + cc) = vd;
    }
}

// ---------------------------------------------------------------------------
extern "C" void kernel_launch(void* const* d_in, const int* in_sizes, int n_in,
                              void* d_out, int out_size, void* d_ws, size_t ws_size,
                              hipStream_t stream)
{
    const float* q     = (const float*)d_in[0];
    const float* kv    = (const float*)d_in[1];
    const float* Wq    = (const float*)d_in[2];
    const float* Wkv   = (const float*)d_in[3];
    const float* Wproj = (const float*)d_in[4];
    const float* bproj = (const float*)d_in[5];
    const int*   mask  = (const int*)d_in[6];
    float* out = (float*)d_out;

    char* ws = (char*)d_ws;
    short* q_h   = (short*)ws; ws += (size_t)4096 * 768 * 2;
    short* kv_h  = (short*)ws; ws += (size_t)8192 * 768 * 2;
    short* Wq_h  = (short*)ws; ws += (size_t)768 * 768 * 2;
    short* Wkv_h = (short*)ws; ws += (size_t)1536 * 768 * 2;
    short* Wp_h  = (short*)ws; ws += (size_t)768 * 768 * 2;
    short* qp    = (short*)ws; ws += (size_t)4096 * 768 * 2;   // [B,H,N,64] fp16
    short* kk    = (short*)ws; ws += (size_t)8192 * 768 * 2;   // [B,H,M,64] fp16
    short* vt    = (short*)ws; ws += (size_t)8192 * 768 * 2;   // [B,H,64,M] fp16
    short* xb    = (short*)ws; ws += (size_t)4096 * 768 * 2;   // [B,N,768]  fp16
    unsigned char* mbytes = (unsigned char*)ws;                // [B,N,M/8] = 1 MB

    prep_kernel<<<9856, 256, 0, stream>>>(q, kv, Wq, Wkv, Wproj, mask,
                                          q_h, kv_h, Wq_h, Wkv_h, Wp_h, mbytes);
    gemm12_kernel<<<960, 256, 0, stream>>>(q_h, Wq_h, kv_h, Wkv_h, qp, kk, vt);
    attn_kernel<<<768, 256, 0, stream>>>(qp, kk, vt, (const unsigned*)mbytes, xb);
    gemm3_kernel<<<192, 256, 0, stream>>>(xb, Wp_h, bproj, out);
}